// Round 14
// baseline (75.659 us; speedup 1.0000x reference)
//
#include <hip/hip_runtime.h>
#include <stdint.h>

// GCMConv on MI355X. Data model (verified rounds 0-3):
//   x      : float32 (1,16384,8,3,3,2)  — complex pair = v2f
//   weight : float32 (4,9,33)
//   out    : float32 (1,16384,8,3,3,2)
//
// M-factorization (16 threads/site: u=out-channel, g=quarter):
//   M[u,v] = sum_w16 ( wt[u,v,w16] t[w16] + wt[u,v,16+w16] t[w16]^+ ) + wt[u,v,32] I
//   out[u] = sum_v w_full[v] @ M[u,v];  thread (u,g) builds M[u,g], M[u,4+g];
//   cc gets the v=8 share from the thread's own w16 quarter.
//
// Round-14: coalesce the COLD global path (phase 1 was unchanged R9-R13 while
// all phase-2 tweaks were ~neutral -> the invariant cost is the scattered
// 8-B neighbor loads). Off-block neighbor w-chunks (axes 0-2, 288 B each)
// staged to LDS via coalesced float4; axis-3 neighbors are in-block (global,
// shares own lines). Weight staging vectorized float4. LDS 39.6 KB -> 4 blk/CU.

typedef float v2f __attribute__((ext_vector_type(2)));

#define SPB 16            // sites per block (= one full d3 line: axis-3 wraps in-block)
#define TPB 256           // 16 threads per site
#define NSITES 16384
#define TS_TILE 10        // v2f per tile (9 + 1 pad)
#define TS2_SITE 164      // v2f per site
#define NWGT 1188         // 4*9*33
#define NCHUNK 48         // 3 axes x 16 sites neighbor w-chunks
#define CH_F4 18          // float4 per 288-B chunk

#if defined(__has_builtin)
#if __has_builtin(__builtin_elementwise_fma)
#define HAVE_EW_FMA 1
#endif
#endif

__device__ __forceinline__ v2f pkfma(v2f a, v2f b, v2f c){
#ifdef HAVE_EW_FMA
    return __builtin_elementwise_fma(a, b, c);
#else
    v2f r; r.x = fmaf(a.x, b.x, c.x); r.y = fmaf(a.y, b.y, c.y); return r;
#endif
}
__device__ __forceinline__ v2f spl(float s){ return (v2f){s, s}; }
__device__ __forceinline__ v2f pn (float s){ return (v2f){s, -s}; }
__device__ __forceinline__ v2f np (float s){ return (v2f){-s, s}; }
__device__ __forceinline__ v2f swp(v2f a){ return __builtin_shufflevector(a, a, 1, 0); }
__device__ __forceinline__ v2f zero2(){ return (v2f){0.f, 0.f}; }

__device__ __forceinline__ int neigh(int s, int a){
    // dims (8,8,16,16): d3 bits[0:4), d2 bits[4:8), d1 bits[8:11), d0 bits[11:14)
    if (a == 3) return (s & ~15)        | ((s + 1)    & 15);
    if (a == 2) return (s & ~(15 << 4)) | ((s + 16)   & (15 << 4));
    if (a == 1) return (s & ~(7 << 8))  | ((s + 256)  & (7 << 8));
    return              (s & ~(7 << 11))| ((s + 2048) & (7 << 11));
}

// load one 9-v2f tile via 4x ds_read_b128 + 1x ds_read_b64
__device__ __forceinline__ void load_tile(v2f* tc, const v2f* tp){
    const float4* tp4 = (const float4*)tp;
    float4 q0 = tp4[0], q1 = tp4[1], q2 = tp4[2], q3 = tp4[3];
    tc[0] = (v2f){q0.x, q0.y}; tc[1] = (v2f){q0.z, q0.w};
    tc[2] = (v2f){q1.x, q1.y}; tc[3] = (v2f){q1.z, q1.w};
    tc[4] = (v2f){q2.x, q2.y}; tc[5] = (v2f){q2.z, q2.w};
    tc[6] = (v2f){q3.x, q3.y}; tc[7] = (v2f){q3.z, q3.w};
    tc[8] = tp[8];
}

__global__ __launch_bounds__(TPB, 2)
void gcm_fused(const float* __restrict__ xp,
               const float* __restrict__ wgt,
               float* __restrict__ outp)
{
    __shared__ alignas(16) v2f lt[SPB * TS2_SITE];           // 20,992 B
    __shared__ alignas(16) float4 nstage[NCHUNK * CH_F4];    // 13,824 B
    __shared__ alignas(16) float wsm[NWGT];                  //  4,752 B
    const v2f* x2 = (const v2f*)xp;
    v2f* o2 = (v2f*)outp;

    const int tid = threadIdx.x;
    const int g   = tid & 3;            // lane bits 0-1 -> shfl_xor reduction
    const int u   = (tid >> 2) & 3;     // output channel / phase1 axis
    const int sl  = tid >> 4;           // site within block
    const int sbase = blockIdx.x * SPB;
    const int s   = sbase + sl;

    // ---- coalesced stage: neighbor w-chunks for axes 0-2 (float4)
    #pragma unroll 1
    for (int idx = tid; idx < NCHUNK * CH_F4; idx += TPB){
        int chunk = idx / CH_F4;          // 0..47
        int r     = idx - chunk * CH_F4;  // 0..17
        int a     = chunk >> 4;           // 0..2
        int sn    = neigh(sbase + (chunk & 15), a);
        const float4* src = (const float4*)(xp + (size_t)(sn * 8 + 4) * 18);
        nstage[chunk * CH_F4 + r] = src[r];
    }
    // ---- stage weights (vectorized float4: 1188 = 297*4)
    #pragma unroll 1
    for (int idx = tid; idx < NWGT / 4; idx += TPB){
        ((float4*)wsm)[idx] = ((const float4*)wgt)[idx];
    }
    __syncthreads();

    // ============ phase 1: one transport per thread: t[u*4+g] = U_u W_g(s+u^) U_u^+
    {
        v2f uc[9], wc[9];
        {
            const v2f* up = x2 + (s * 8 + u) * 9;
            #pragma unroll
            for (int e = 0; e < 9; e++) uc[e] = up[e];
        }
        if (u < 3){
            const v2f* wp = (const v2f*)nstage + ((u * 16 + sl) * 36 + g * 9);
            #pragma unroll
            for (int e = 0; e < 9; e++) wc[e] = wp[e];
        } else {
            const int sn = neigh(s, 3);   // in-block neighbor
            const v2f* wp = x2 + (sn * 8 + 4 + g) * 9;
            #pragma unroll
            for (int e = 0; e < 9; e++) wc[e] = wp[e];
        }
        // T1 = U * W
        v2f t1[9];
        #pragma unroll
        for (int r = 0; r < 3; r++){
            #pragma unroll
            for (int k = 0; k < 3; k++){
                v2f acc = zero2();
                #pragma unroll
                for (int j = 0; j < 3; j++){
                    v2f a_ = uc[r*3+j], b_ = wc[j*3+k];
                    acc = pkfma(spl(a_.x), b_, acc);
                    acc = pkfma(np(a_.y), swp(b_), acc);
                }
                t1[r*3+k] = acc;
            }
        }
        // T = T1 * U^+ ; b128 writes
        v2f tt[9];
        #pragma unroll
        for (int r = 0; r < 3; r++){
            #pragma unroll
            for (int k = 0; k < 3; k++){
                v2f acc = zero2();
                #pragma unroll
                for (int j = 0; j < 3; j++){
                    v2f a_ = t1[r*3+j], b_ = uc[k*3+j];
                    acc = pkfma(pn(a_.x), b_, acc);
                    acc = pkfma(spl(a_.y), swp(b_), acc);
                }
                tt[r*3+k] = acc;
            }
        }
        v2f* dst = &lt[sl * TS2_SITE + (u * 4 + g) * TS_TILE];
        float4* dst4 = (float4*)dst;
        dst4[0] = make_float4(tt[0].x, tt[0].y, tt[1].x, tt[1].y);
        dst4[1] = make_float4(tt[2].x, tt[2].y, tt[3].x, tt[3].y);
        dst4[2] = make_float4(tt[4].x, tt[4].y, tt[5].x, tt[5].y);
        dst4[3] = make_float4(tt[6].x, tt[6].y, tt[7].x, tt[7].y);
        dst[8] = tt[8];
    }
    __syncthreads();

    // ============ phase 2 ============
    // pass-through copy of u channels (one quarter of lanes)
    if (g == 1){
        const v2f* src = x2 + (s * 8 + u) * 9;
        v2f* dst = o2 + (s * 8 + u) * 9;
        #pragma unroll
        for (int e = 0; e < 9; e++) dst[e] = src[e];
    }

    v2f M1[9], M2[9];
    #pragma unroll
    for (int e = 0; e < 9; e++){ M1[e] = zero2(); M2[e] = zero2(); }

    const float* wu  = wsm + u * 297;    // weight[u][v][w], stride 33 per v
    const float* wuA = wu + g * 33;      // v = g
    const float* wuB = wu + (4 + g) * 33;// v = 4+g
    const float* wu8 = wu + 8 * 33;      // v = 8

    const v2f* tbase = &lt[sl * TS2_SITE];

    // ---- main loop: M1/M2 only; w16 uniform across lanes (broadcast LDS reads)
    #pragma unroll 1
    for (int w16 = 0; w16 < 16; w16++){
        v2f tc[9];
        load_tile(tc, tbase + w16 * TS_TILE);
        float a1 = wuA[w16], b1 = wuA[16 + w16];
        float a2 = wuB[w16], b2 = wuB[16 + w16];
        #pragma unroll
        for (int i = 0; i < 3; i++){
            #pragma unroll
            for (int j = 0; j < 3; j++){
                const int e = i*3+j, eT = j*3+i;
                M1[e] = pkfma(spl(a1), tc[e],  M1[e]);
                M1[e] = pkfma(pn(b1),  tc[eT], M1[e]);
                M2[e] = pkfma(spl(a2), tc[e],  M2[e]);
                M2[e] = pkfma(pn(b2),  tc[eT], M2[e]);
            }
        }
    }

    // ---- cc: v=8 share over this thread's own quarter (w16 = 4g+it)
    v2f cc[9];
    #pragma unroll
    for (int e = 0; e < 9; e++) cc[e] = zero2();
    #pragma unroll 1
    for (int it = 0; it < 4; it++){
        const int w16 = g * 4 + it;
        v2f tc[9];
        load_tile(tc, tbase + w16 * TS_TILE);
        float c8 = wu8[w16], d8 = wu8[16 + w16];
        #pragma unroll
        for (int i = 0; i < 3; i++){
            #pragma unroll
            for (int j = 0; j < 3; j++){
                const int e = i*3+j, eT = j*3+i;
                cc[e] = pkfma(spl(c8), tc[e],  cc[e]);
                cc[e] = pkfma(pn(d8),  tc[eT], cc[e]);
            }
        }
    }

    // ---- identity (w=32) contributions to the diagonals
    {
        float c1 = wuA[32], c2 = wuB[32];
        M1[0].x += c1; M1[4].x += c1; M1[8].x += c1;
        M2[0].x += c2; M2[4].x += c2; M2[8].x += c2;
        if (g == 0){
            float e8 = wu8[32];
            cc[0].x += e8; cc[4].x += e8; cc[8].x += e8;
        }
    }

    // ---- wg loaded late (R12: early-issue neutral)
    v2f wg[9];
    {
        const v2f* wp = x2 + (s * 8 + 4 + g) * 9;
        #pragma unroll
        for (int e = 0; e < 9; e++) wg[e] = wp[e];
    }

    // ---- epilogue: cc += w[g] @ M1 + w[g]^+ @ M2
    #pragma unroll
    for (int i = 0; i < 3; i++){
        #pragma unroll
        for (int k = 0; k < 3; k++){
            v2f acc = cc[i*3+k];
            #pragma unroll
            for (int j = 0; j < 3; j++){
                v2f a_ = wg[i*3+j];
                v2f m  = M1[j*3+k];
                acc = pkfma(spl(a_.x), m,      acc);   // (ax*mr, ax*mi)
                acc = pkfma(np(a_.y),  swp(m), acc);   // (-ay*mi, ay*mr)
            }
            #pragma unroll
            for (int j = 0; j < 3; j++){
                v2f b_ = wg[j*3+i];                    // conj-transpose source
                v2f m  = M2[j*3+k];
                acc = pkfma(spl(b_.x), m,      acc);   // (bx*mr, bx*mi)
                acc = pkfma(pn(b_.y),  swp(m), acc);   // (by*mi, -by*mr)
            }
            cc[i*3+k] = acc;
        }
    }

    // --- reduce partials over g (lane bits 0-1) and store
    #pragma unroll
    for (int e = 0; e < 9; e++){
        cc[e].x += __shfl_xor(cc[e].x, 1);
        cc[e].x += __shfl_xor(cc[e].x, 2);
        cc[e].y += __shfl_xor(cc[e].y, 1);
        cc[e].y += __shfl_xor(cc[e].y, 2);
    }
    if (g == 0){
        v2f* dst = o2 + (s * 8 + 4 + u) * 9;
        #pragma unroll
        for (int e = 0; e < 9; e++) dst[e] = cc[e];
    }
}

extern "C" void kernel_launch(void* const* d_in, const int* in_sizes, int n_in,
                              void* d_out, int out_size, void* d_ws, size_t ws_size,
                              hipStream_t stream)
{
    const float* x = (const float*)d_in[0];
    const float* w = (const float*)d_in[1];
    float* out = (float*)d_out;
    dim3 grid(NSITES / SPB);
    dim3 block(TPB);
    hipLaunchKernelGGL(gcm_fused, grid, block, 0, stream, x, w, out);
}